// Round 1
// baseline (556.756 us; speedup 1.0000x reference)
//
#include <hip/hip_runtime.h>
#include <math.h>

// Problem constants
#define B_   16
#define L_   512
#define ENC  7
#define DM   512
#define DIN  1024
#define XZC  2048   // 2*DIN
#define DSTATE 16
#define DCONV  4
#define DTRANK 32
#define COUT 7
#define PRED 96
#define L0T  (L_ - PRED)   // 416

__device__ __forceinline__ float sigmoidf_(float x) { return 1.f / (1.f + __expf(-x)); }
__device__ __forceinline__ float siluf_(float x) { return x * sigmoidf_(x); }
__device__ __forceinline__ float softplusf_(float x) {
    return (x > 20.f) ? x : log1pf(__expf(x));
}

// ---------------------------------------------------------------- norm ----
// grid 112 (b*7+c), block 256. mean/std over L, write xn.
__global__ void norm_kernel(const float* __restrict__ x, float* __restrict__ xn,
                            float* __restrict__ mean, float* __restrict__ stdv) {
    int bc = blockIdx.x;
    int b = bc / ENC, c = bc % ENC;
    int tid = threadIdx.x;
    float s = 0.f, s2 = 0.f;
    for (int l = tid; l < L_; l += 256) {
        float v = x[(b * L_ + l) * ENC + c];
        s += v; s2 += v * v;
    }
    #pragma unroll
    for (int off = 32; off; off >>= 1) {
        s  += __shfl_down(s, off);
        s2 += __shfl_down(s2, off);
    }
    __shared__ float rs[4], rs2[4], sm, ssd;
    int wave = tid >> 6, lane = tid & 63;
    if (lane == 0) { rs[wave] = s; rs2[wave] = s2; }
    __syncthreads();
    if (tid == 0) {
        float S = rs[0] + rs[1] + rs[2] + rs[3];
        float S2 = rs2[0] + rs2[1] + rs2[2] + rs2[3];
        float m = S / (float)L_;
        float var = S2 / (float)L_ - m * m;
        float sd = sqrtf(var + 1e-5f);
        mean[bc] = m; stdv[bc] = sd;
        sm = m; ssd = sd;
    }
    __syncthreads();
    float m = sm, sd = ssd;
    for (int l = tid; l < L_; l += 256) {
        int idx = (b * L_ + l) * ENC + c;
        xn[idx] = (x[idx] - m) / sd;
    }
}

// ---------------------------------------------------------- weight folds ----
// W_ek[k,c,j] = sum_d W_emb[k,c,d] * W_in[d,j]   (3*7*2048 outputs)
__global__ void fold_wek(const float* __restrict__ W_emb, const float* __restrict__ W_in,
                         float* __restrict__ W_ek) {
    int o = blockIdx.x * 256 + threadIdx.x;      // < 43008
    int j = o & (XZC - 1);
    int kc = o >> 11;                            // k*7+c
    const float* we = W_emb + kc * DM;
    float s = 0.f;
    for (int d = 0; d < DM; ++d) s = fmaf(we[d], W_in[d * XZC + j], s);
    W_ek[o] = s;
}

// W_oh[j,c] = sum_d W_out[j,d]*W_head[d,c]   (1024*7 outputs)
__global__ void fold_woh(const float* __restrict__ W_out, const float* __restrict__ W_head,
                         float* __restrict__ W_oh) {
    int o = blockIdx.x * 256 + threadIdx.x;      // < 7168
    int c = o % COUT, j = o / COUT;
    float s = 0.f;
    for (int d = 0; d < DM; ++d) s = fmaf(W_out[j * DM + d], W_head[d * COUT + c], s);
    W_oh[o] = s;
}

// ------------------------------------------------------------------ pe ----
__global__ void pe_kernel(float* __restrict__ pe) {
    int o = blockIdx.x * 256 + threadIdx.x;      // < 512*512
    int dcol = o & (DM - 1), l = o >> 9;
    int i2 = dcol >> 1;
    // div_i = exp(-(2i) * ln(10000)/512)
    float div = __expf(-(float)(2 * i2) * (9.210340371976184f / (float)DM));
    float arg = (float)l * div;
    pe[o] = (dcol & 1) ? cosf(arg) : sinf(arg);
}

// ------------------------------------------------- peW = pe @ W_in GEMM ----
// A: 512x512, B: 512x2048, C: 512x2048. grid (32,8), block 256, 64x64 tile.
__global__ __launch_bounds__(256) void gemm_peW(const float* __restrict__ A,
                                                const float* __restrict__ Bm,
                                                float* __restrict__ C) {
    int n0 = blockIdx.x * 64, m0 = blockIdx.y * 64;
    int tid = threadIdx.x;
    int tx = tid & 15, ty = tid >> 4;
    __shared__ float As[16][64];
    __shared__ float Bs[16][64];
    float acc[4][4] = {};
    for (int k0 = 0; k0 < DM; k0 += 16) {
        __syncthreads();
        #pragma unroll
        for (int q = 0; q < 4; ++q) {
            int f = tid + q * 256;
            int r = f >> 4, kk = f & 15;
            As[kk][r] = A[(m0 + r) * DM + k0 + kk];
        }
        #pragma unroll
        for (int q = 0; q < 4; ++q) {
            int f = tid + q * 256;
            int kk = f >> 6, c = f & 63;
            Bs[kk][c] = Bm[(k0 + kk) * XZC + n0 + c];
        }
        __syncthreads();
        #pragma unroll
        for (int kk = 0; kk < 16; ++kk) {
            float a[4], bb[4];
            #pragma unroll
            for (int i = 0; i < 4; ++i) a[i] = As[kk][ty * 4 + i];
            #pragma unroll
            for (int j = 0; j < 4; ++j) bb[j] = Bs[kk][tx * 4 + j];
            #pragma unroll
            for (int i = 0; i < 4; ++i)
                #pragma unroll
                for (int j = 0; j < 4; ++j) acc[i][j] = fmaf(a[i], bb[j], acc[i][j]);
        }
    }
    #pragma unroll
    for (int i = 0; i < 4; ++i)
        #pragma unroll
        for (int j = 0; j < 4; ++j)
            C[(m0 + ty * 4 + i) * XZC + n0 + tx * 4 + j] = acc[i][j];
}

// --------------------------------------- fused xm + depthwise conv + silu ----
// u[b,l,j] = silu( sum_k xm[b,l-3+k,j]*cw[k] + cb[j] ),
// xm[b,l,j] = sum_{k,c} xn[b,wrap(l+k-1),c]*W_ek[k,c,j] + peW[l,j]
// grid (DIN/64, L/64, B), block 256
__global__ __launch_bounds__(256) void u_kernel(const float* __restrict__ xn,
        const float* __restrict__ W_ek, const float* __restrict__ peW,
        const float* __restrict__ conv_w, const float* __restrict__ conv_b,
        float* __restrict__ u) {
    int b = blockIdx.z, l0 = blockIdx.y * 64, j0 = blockIdx.x * 64;
    int tid = threadIdx.x;
    int jl = tid & 63, lq = tid >> 6;
    int jg = j0 + jl;
    __shared__ float xmT[67][64];
    float wek[3][7];
    #pragma unroll
    for (int k = 0; k < 3; ++k)
        #pragma unroll
        for (int c = 0; c < 7; ++c)
            wek[k][c] = W_ek[(k * 7 + c) * XZC + jg];
    for (int r = lq; r < 67; r += 4) {
        int l = l0 - 3 + r;
        float v = 0.f;
        if (l >= 0) {
            v = peW[l * XZC + jg];
            #pragma unroll
            for (int k = 0; k < 3; ++k) {
                int lw = l + k - 1;
                lw = (lw < 0) ? (L_ - 1) : ((lw >= L_) ? lw - L_ : lw);
                const float* xr = xn + (b * L_ + lw) * ENC;
                #pragma unroll
                for (int c = 0; c < 7; ++c) v = fmaf(xr[c], wek[k][c], v);
            }
        }
        xmT[r][jl] = v;
    }
    __syncthreads();
    float cw0 = conv_w[0 * DIN + jg], cw1 = conv_w[1 * DIN + jg];
    float cw2 = conv_w[2 * DIN + jg], cw3 = conv_w[3 * DIN + jg];
    float cb = conv_b[jg];
    for (int r = lq; r < 64; r += 4) {
        int l = l0 + r;
        float s = cb;
        s = fmaf(xmT[r + 0][jl], cw0, s);
        s = fmaf(xmT[r + 1][jl], cw1, s);
        s = fmaf(xmT[r + 2][jl], cw2, s);
        s = fmaf(xmT[r + 3][jl], cw3, s);
        u[((b * L_) + l) * DIN + jg] = siluf_(s);
    }
}

// -------------------------------------------- zs = silu(z) for last 96 t ----
// grid (4, 6, 16), block 256
__global__ void z_kernel(const float* __restrict__ xn, const float* __restrict__ W_ek,
                         const float* __restrict__ peW, float* __restrict__ zs) {
    int jg = blockIdx.x * 256 + threadIdx.x;   // 0..1023
    int b = blockIdx.z;
    int col = DIN + jg;
    float wek[3][7];
    #pragma unroll
    for (int k = 0; k < 3; ++k)
        #pragma unroll
        for (int c = 0; c < 7; ++c)
            wek[k][c] = W_ek[(k * 7 + c) * XZC + col];
    for (int i = 0; i < 16; ++i) {
        int t96 = blockIdx.y * 16 + i;
        int l = L0T + t96;
        float v = peW[l * XZC + col];
        #pragma unroll
        for (int k = 0; k < 3; ++k) {
            int lw = l + k - 1;
            if (lw >= L_) lw -= L_;
            const float* xr = xn + (b * L_ + lw) * ENC;
            #pragma unroll
            for (int c = 0; c < 7; ++c) v = fmaf(xr[c], wek[k][c], v);
        }
        zs[((b * PRED) + t96) * DIN + jg] = siluf_(v);
    }
}

// --------------------------------------------------- dbc = u @ W_xproj ----
// M=8192, N=64, K=1024. grid 512 (16 rows each), block 256.
__global__ __launch_bounds__(256) void dbc_kernel(const float* __restrict__ u,
        const float* __restrict__ Wx, float* __restrict__ dbc) {
    int row0 = blockIdx.x * 16;
    int tid = threadIdx.x;
    int n = tid & 63, rq = tid >> 6;
    __shared__ float us[16][128];
    float acc[4] = {0.f, 0.f, 0.f, 0.f};
    for (int k0 = 0; k0 < DIN; k0 += 128) {
        __syncthreads();
        #pragma unroll
        for (int q = 0; q < 8; ++q) {
            int f = tid + q * 256;
            int r = f >> 7, kk = f & 127;
            us[r][kk] = u[(row0 + r) * DIN + k0 + kk];
        }
        __syncthreads();
        for (int kk = 0; kk < 128; ++kk) {
            float w = Wx[(k0 + kk) * 64 + n];
            #pragma unroll
            for (int rr = 0; rr < 4; ++rr) acc[rr] = fmaf(us[rq + rr * 4][kk], w, acc[rr]);
        }
    }
    #pragma unroll
    for (int rr = 0; rr < 4; ++rr)
        dbc[(row0 + rq + rr * 4) * 64 + n] = acc[rr];
}

// ------------------------------- dt = softplus(dbc[:, :32] @ W_dt + b_dt) ----
// grid (4, 512), block 256. 16 rows x 256 cols per block.
__global__ __launch_bounds__(256) void dt_kernel(const float* __restrict__ dbc,
        const float* __restrict__ W_dt, const float* __restrict__ b_dt,
        float* __restrict__ dt) {
    int jg = blockIdx.x * 256 + threadIdx.x;
    int r0 = blockIdx.y * 16;
    int tid = threadIdx.x;
    float wdt[32];
    #pragma unroll
    for (int k = 0; k < 32; ++k) wdt[k] = W_dt[k * DIN + jg];
    __shared__ float dsm[16][32];
    #pragma unroll
    for (int q = 0; q < 2; ++q) {
        int f = tid + q * 256;
        int r = f >> 5, kk = f & 31;
        dsm[r][kk] = dbc[(r0 + r) * 64 + kk];
    }
    __syncthreads();
    float bd = b_dt[jg];
    for (int r = 0; r < 16; ++r) {
        float s = bd;
        #pragma unroll
        for (int k = 0; k < 32; ++k) s = fmaf(dsm[r][k], wdt[k], s);
        dt[(r0 + r) * DIN + jg] = softplusf_(s);
    }
}

// ------------------------------------------------------- selective scan ----
// grid (4, 16): 256 d per block, one b per blockIdx.y. Writes
// yfin[b,t96,d] = (y + u*D) * zs for t >= 416.
__global__ __launch_bounds__(256) void scan_kernel(const float* __restrict__ dt,
        const float* __restrict__ u, const float* __restrict__ dbc,
        const float* __restrict__ zs, const float* __restrict__ A_log,
        const float* __restrict__ Dv, float* __restrict__ yfin) {
    int b = blockIdx.y;
    int d = blockIdx.x * 256 + threadIdx.x;
    float An[DSTATE], h[DSTATE];
    #pragma unroll
    for (int n = 0; n < DSTATE; ++n) {
        An[n] = -__expf(A_log[d * DSTATE + n]);
        h[n] = 0.f;
    }
    float Dd = Dv[d];
    for (int t = 0; t < L_; ++t) {
        int row = b * L_ + t;
        float dtv = dt[row * DIN + d];
        float uv = u[row * DIN + d];
        const float* bc = dbc + row * 64;
        float du = dtv * uv;
        float y = 0.f;
        #pragma unroll
        for (int n = 0; n < DSTATE; ++n) {
            float dA = __expf(dtv * An[n]);
            h[n] = fmaf(dA, h[n], du * bc[32 + n]);
            y = fmaf(h[n], bc[48 + n], y);
        }
        if (t >= L0T) {
            int idx = ((b * PRED) + (t - L0T)) * DIN + d;
            yfin[idx] = (y + uv * Dd) * zs[idx];
        }
    }
}

// ------------------------------------------------------- final project ----
// out[b,t,c] = (sum_j yfin*W_oh[j,c]) * std[b,c] + mean[b,c]
// grid (96, 16), block 64.
__global__ void final_kernel(const float* __restrict__ yfin, const float* __restrict__ W_oh,
                             const float* __restrict__ mean, const float* __restrict__ stdv,
                             float* __restrict__ out) {
    int t96 = blockIdx.x, b = blockIdx.y;
    int lane = threadIdx.x;
    float p[COUT] = {};
    int base = ((b * PRED) + t96) * DIN;
    for (int j = lane; j < DIN; j += 64) {
        float yv = yfin[base + j];
        #pragma unroll
        for (int c = 0; c < COUT; ++c) p[c] = fmaf(yv, W_oh[j * COUT + c], p[c]);
    }
    #pragma unroll
    for (int off = 32; off; off >>= 1)
        #pragma unroll
        for (int c = 0; c < COUT; ++c) p[c] += __shfl_down(p[c], off);
    if (lane == 0) {
        #pragma unroll
        for (int c = 0; c < COUT; ++c)
            out[((b * PRED) + t96) * COUT + c] = p[c] * stdv[b * COUT + c] + mean[b * COUT + c];
    }
}

extern "C" void kernel_launch(void* const* d_in, const int* in_sizes, int n_in,
                              void* d_out, int out_size, void* d_ws, size_t ws_size,
                              hipStream_t stream) {
    const float* x_enc  = (const float*)d_in[0];
    const float* W_emb  = (const float*)d_in[1];
    const float* W_in   = (const float*)d_in[2];
    const float* conv_w = (const float*)d_in[3];
    const float* conv_b = (const float*)d_in[4];
    const float* W_xp   = (const float*)d_in[5];
    const float* W_dt   = (const float*)d_in[6];
    const float* b_dt   = (const float*)d_in[7];
    const float* A_log  = (const float*)d_in[8];
    const float* Dv     = (const float*)d_in[9];
    const float* W_out  = (const float*)d_in[10];
    const float* W_head = (const float*)d_in[11];
    float* out = (float*)d_out;

    float* W = (float*)d_ws;
    float* xn   = W;              W += B_ * L_ * ENC;        // 57344
    float* mean = W;              W += B_ * ENC;             // 112
    float* stdv = W;              W += B_ * ENC;             // 112
    float* W_ek = W;              W += 3 * ENC * XZC;        // 43008
    float* W_oh = W;              W += DIN * COUT;           // 7168
    float* pe   = W;              W += L_ * DM;              // 262144
    float* peW  = W;              W += L_ * XZC;             // 1048576
    float* u    = W;              W += B_ * L_ * DIN;        // 8388608
    float* zs   = W;              W += B_ * PRED * DIN;      // 1572864
    float* dbc  = W;              W += B_ * L_ * 64;         // 524288
    float* dt   = W;              W += B_ * L_ * DIN;        // 8388608
    float* yfin = W;              W += B_ * PRED * DIN;      // 1572864

    norm_kernel<<<B_ * ENC, 256, 0, stream>>>(x_enc, xn, mean, stdv);
    fold_wek<<<(3 * ENC * XZC) / 256, 256, 0, stream>>>(W_emb, W_in, W_ek);
    fold_woh<<<(DIN * COUT) / 256, 256, 0, stream>>>(W_out, W_head, W_oh);
    pe_kernel<<<(L_ * DM) / 256, 256, 0, stream>>>(pe);
    gemm_peW<<<dim3(XZC / 64, L_ / 64), 256, 0, stream>>>(pe, W_in, peW);
    u_kernel<<<dim3(DIN / 64, L_ / 64, B_), 256, 0, stream>>>(xn, W_ek, peW, conv_w, conv_b, u);
    z_kernel<<<dim3(4, 6, B_), 256, 0, stream>>>(xn, W_ek, peW, zs);
    dbc_kernel<<<(B_ * L_) / 16, 256, 0, stream>>>(u, W_xp, dbc);
    dt_kernel<<<dim3(4, (B_ * L_) / 16), 256, 0, stream>>>(dbc, W_dt, b_dt, dt);
    scan_kernel<<<dim3(4, B_), 256, 0, stream>>>(dt, u, dbc, zs, A_log, Dv, yfin);
    final_kernel<<<dim3(PRED, B_), 64, 0, stream>>>(yfin, W_oh, mean, stdv, out);
}

// Round 2
// 359.895 us; speedup vs baseline: 1.5470x; 1.5470x over previous
//
#include <hip/hip_runtime.h>
#include <math.h>

// Problem constants
#define B_   16
#define L_   512
#define ENC  7
#define DM   512
#define DIN  1024
#define XZC  2048   // 2*DIN
#define DSTATE 16
#define DCONV  4
#define DTRANK 32
#define COUT 7
#define PRED 96
#define L0T  (L_ - PRED)   // 416
#define NCH  16
#define CLEN 32            // L_/NCH

__device__ __forceinline__ float sigmoidf_(float x) { return 1.f / (1.f + __expf(-x)); }
__device__ __forceinline__ float siluf_(float x) { return x * sigmoidf_(x); }
__device__ __forceinline__ float softplusf_(float x) {
    return (x > 20.f) ? x : log1pf(__expf(x));
}

// ---------------------------------------------------------------- norm ----
__global__ void norm_kernel(const float* __restrict__ x, float* __restrict__ xn,
                            float* __restrict__ mean, float* __restrict__ stdv) {
    int bc = blockIdx.x;
    int b = bc / ENC, c = bc % ENC;
    int tid = threadIdx.x;
    float s = 0.f, s2 = 0.f;
    for (int l = tid; l < L_; l += 256) {
        float v = x[(b * L_ + l) * ENC + c];
        s += v; s2 += v * v;
    }
    #pragma unroll
    for (int off = 32; off; off >>= 1) {
        s  += __shfl_down(s, off);
        s2 += __shfl_down(s2, off);
    }
    __shared__ float rs[4], rs2[4], sm, ssd;
    int wave = tid >> 6, lane = tid & 63;
    if (lane == 0) { rs[wave] = s; rs2[wave] = s2; }
    __syncthreads();
    if (tid == 0) {
        float S = rs[0] + rs[1] + rs[2] + rs[3];
        float S2 = rs2[0] + rs2[1] + rs2[2] + rs2[3];
        float m = S / (float)L_;
        float var = S2 / (float)L_ - m * m;
        float sd = sqrtf(var + 1e-5f);
        mean[bc] = m; stdv[bc] = sd;
        sm = m; ssd = sd;
    }
    __syncthreads();
    float m = sm, sd = ssd;
    for (int l = tid; l < L_; l += 256) {
        int idx = (b * L_ + l) * ENC + c;
        xn[idx] = (x[idx] - m) / sd;
    }
}

// ---------------------------------------------------------- weight folds ----
__global__ void fold_wek(const float* __restrict__ W_emb, const float* __restrict__ W_in,
                         float* __restrict__ W_ek) {
    int o = blockIdx.x * 256 + threadIdx.x;      // < 43008
    int j = o & (XZC - 1);
    int kc = o >> 11;                            // k*7+c
    const float* we = W_emb + kc * DM;
    float s = 0.f;
    for (int d = 0; d < DM; ++d) s = fmaf(we[d], W_in[d * XZC + j], s);
    W_ek[o] = s;
}

__global__ void fold_woh(const float* __restrict__ W_out, const float* __restrict__ W_head,
                         float* __restrict__ W_oh) {
    int o = blockIdx.x * 256 + threadIdx.x;      // < 7168
    int c = o % COUT, j = o / COUT;
    float s = 0.f;
    for (int d = 0; d < DM; ++d) s = fmaf(W_out[j * DM + d], W_head[d * COUT + c], s);
    W_oh[o] = s;
}

// ------------------------------------------------------------------ pe ----
__global__ void pe_kernel(float* __restrict__ pe) {
    int o = blockIdx.x * 256 + threadIdx.x;      // < 512*512
    int dcol = o & (DM - 1), l = o >> 9;
    int i2 = dcol >> 1;
    float div = __expf(-(float)(2 * i2) * (9.210340371976184f / (float)DM));
    float arg = (float)l * div;
    pe[o] = (dcol & 1) ? cosf(arg) : sinf(arg);
}

// ------------------------------------------------- peW = pe @ W_in GEMM ----
// Region-trimmed: cols [0,1024) need all rows; cols [1024,2048) need rows>=416
// (computed as rows 384..511). 1D grid of 160 blocks, 64x64 tiles.
__global__ __launch_bounds__(256) void gemm_peW(const float* __restrict__ A,
                                                const float* __restrict__ Bm,
                                                float* __restrict__ C) {
    int bid = blockIdx.x;
    int m0, n0;
    if (bid < 128) { m0 = (bid >> 4) * 64; n0 = (bid & 15) * 64; }
    else { int q = bid - 128; m0 = 384 + (q >> 4) * 64; n0 = 1024 + (q & 15) * 64; }
    int tid = threadIdx.x;
    int tx = tid & 15, ty = tid >> 4;
    __shared__ float As[16][64];
    __shared__ float Bs[16][64];
    float acc[4][4] = {};
    for (int k0 = 0; k0 < DM; k0 += 16) {
        __syncthreads();
        #pragma unroll
        for (int q = 0; q < 4; ++q) {
            int f = tid + q * 256;
            int r = f >> 4, kk = f & 15;
            As[kk][r] = A[(m0 + r) * DM + k0 + kk];
        }
        #pragma unroll
        for (int q = 0; q < 4; ++q) {
            int f = tid + q * 256;
            int kk = f >> 6, c = f & 63;
            Bs[kk][c] = Bm[(k0 + kk) * XZC + n0 + c];
        }
        __syncthreads();
        #pragma unroll
        for (int kk = 0; kk < 16; ++kk) {
            float a[4], bb[4];
            #pragma unroll
            for (int i = 0; i < 4; ++i) a[i] = As[kk][ty * 4 + i];
            #pragma unroll
            for (int j = 0; j < 4; ++j) bb[j] = Bs[kk][tx * 4 + j];
            #pragma unroll
            for (int i = 0; i < 4; ++i)
                #pragma unroll
                for (int j = 0; j < 4; ++j) acc[i][j] = fmaf(a[i], bb[j], acc[i][j]);
        }
    }
    #pragma unroll
    for (int i = 0; i < 4; ++i)
        #pragma unroll
        for (int j = 0; j < 4; ++j)
            C[(m0 + ty * 4 + i) * XZC + n0 + tx * 4 + j] = acc[i][j];
}

// --------------------------------------- fused xm + depthwise conv + silu ----
__global__ __launch_bounds__(256) void u_kernel(const float* __restrict__ xn,
        const float* __restrict__ W_ek, const float* __restrict__ peW,
        const float* __restrict__ conv_w, const float* __restrict__ conv_b,
        float* __restrict__ u) {
    int b = blockIdx.z, l0 = blockIdx.y * 64, j0 = blockIdx.x * 64;
    int tid = threadIdx.x;
    int jl = tid & 63, lq = tid >> 6;
    int jg = j0 + jl;
    __shared__ float xmT[67][64];
    float wek[3][7];
    #pragma unroll
    for (int k = 0; k < 3; ++k)
        #pragma unroll
        for (int c = 0; c < 7; ++c)
            wek[k][c] = W_ek[(k * 7 + c) * XZC + jg];
    for (int r = lq; r < 67; r += 4) {
        int l = l0 - 3 + r;
        float v = 0.f;
        if (l >= 0) {
            v = peW[l * XZC + jg];
            #pragma unroll
            for (int k = 0; k < 3; ++k) {
                int lw = l + k - 1;
                lw = (lw < 0) ? (L_ - 1) : ((lw >= L_) ? lw - L_ : lw);
                const float* xr = xn + (b * L_ + lw) * ENC;
                #pragma unroll
                for (int c = 0; c < 7; ++c) v = fmaf(xr[c], wek[k][c], v);
            }
        }
        xmT[r][jl] = v;
    }
    __syncthreads();
    float cw0 = conv_w[0 * DIN + jg], cw1 = conv_w[1 * DIN + jg];
    float cw2 = conv_w[2 * DIN + jg], cw3 = conv_w[3 * DIN + jg];
    float cb = conv_b[jg];
    for (int r = lq; r < 64; r += 4) {
        int l = l0 + r;
        float s = cb;
        s = fmaf(xmT[r + 0][jl], cw0, s);
        s = fmaf(xmT[r + 1][jl], cw1, s);
        s = fmaf(xmT[r + 2][jl], cw2, s);
        s = fmaf(xmT[r + 3][jl], cw3, s);
        u[((b * L_) + l) * DIN + jg] = siluf_(s);
    }
}

// -------------------------------------------- zs = silu(z) for last 96 t ----
__global__ void z_kernel(const float* __restrict__ xn, const float* __restrict__ W_ek,
                         const float* __restrict__ peW, float* __restrict__ zs) {
    int jg = blockIdx.x * 256 + threadIdx.x;   // 0..1023
    int b = blockIdx.z;
    int col = DIN + jg;
    float wek[3][7];
    #pragma unroll
    for (int k = 0; k < 3; ++k)
        #pragma unroll
        for (int c = 0; c < 7; ++c)
            wek[k][c] = W_ek[(k * 7 + c) * XZC + col];
    for (int i = 0; i < 16; ++i) {
        int t96 = blockIdx.y * 16 + i;
        int l = L0T + t96;
        float v = peW[l * XZC + col];
        #pragma unroll
        for (int k = 0; k < 3; ++k) {
            int lw = l + k - 1;
            if (lw >= L_) lw -= L_;
            const float* xr = xn + (b * L_ + lw) * ENC;
            #pragma unroll
            for (int c = 0; c < 7; ++c) v = fmaf(xr[c], wek[k][c], v);
        }
        zs[((b * PRED) + t96) * DIN + jg] = siluf_(v);
    }
}

// --------------------------------------------------- dbc = u @ W_xproj ----
__global__ __launch_bounds__(256) void dbc_kernel(const float* __restrict__ u,
        const float* __restrict__ Wx, float* __restrict__ dbc) {
    int row0 = blockIdx.x * 16;
    int tid = threadIdx.x;
    int n = tid & 63, rq = tid >> 6;
    __shared__ float us[16][128];
    float acc[4] = {0.f, 0.f, 0.f, 0.f};
    for (int k0 = 0; k0 < DIN; k0 += 128) {
        __syncthreads();
        #pragma unroll
        for (int q = 0; q < 8; ++q) {
            int f = tid + q * 256;
            int r = f >> 7, kk = f & 127;
            us[r][kk] = u[(row0 + r) * DIN + k0 + kk];
        }
        __syncthreads();
        for (int kk = 0; kk < 128; ++kk) {
            float w = Wx[(k0 + kk) * 64 + n];
            #pragma unroll
            for (int rr = 0; rr < 4; ++rr) acc[rr] = fmaf(us[rq + rr * 4][kk], w, acc[rr]);
        }
    }
    #pragma unroll
    for (int rr = 0; rr < 4; ++rr)
        dbc[(row0 + rq + rr * 4) * 64 + n] = acc[rr];
}

// ------------------------------------------------- chunked scan: phase A ----
// grid (DIN/256, NCH, B_). Local scan with h=0; dt fused (softplus of
// dbc[:, :32] @ W_dt + b_dt). Outputs per-(b,ch,d): partial h (16) and sum_dt.
__global__ __launch_bounds__(256) void scanA(const float* __restrict__ u,
        const float* __restrict__ dbc, const float* __restrict__ W_dt,
        const float* __restrict__ b_dt, const float* __restrict__ A_log,
        float* __restrict__ part, float* __restrict__ sdt) {
    int b = blockIdx.z, ch = blockIdx.y;
    int d = blockIdx.x * 256 + threadIdx.x;
    int tid = threadIdx.x;
    __shared__ float ds[CLEN][64];
    int row0 = b * L_ + ch * CLEN;
    {
        const float4* src = (const float4*)(dbc + row0 * 64);
        float4* dst = (float4*)&ds[0][0];
        dst[tid] = src[tid];
        dst[tid + 256] = src[tid + 256];
    }
    float wdt[DTRANK];
    #pragma unroll
    for (int k = 0; k < DTRANK; ++k) wdt[k] = W_dt[k * DIN + d];
    float bd = b_dt[d];
    float An[DSTATE], h[DSTATE];
    #pragma unroll
    for (int n = 0; n < DSTATE; ++n) { An[n] = -__expf(A_log[d * DSTATE + n]); h[n] = 0.f; }
    float s = 0.f;
    __syncthreads();
    for (int t = 0; t < CLEN; ++t) {
        float acc = bd;
        #pragma unroll
        for (int g = 0; g < 8; ++g) {
            float4 dv = *(const float4*)&ds[t][g * 4];
            acc = fmaf(dv.x, wdt[g * 4 + 0], acc);
            acc = fmaf(dv.y, wdt[g * 4 + 1], acc);
            acc = fmaf(dv.z, wdt[g * 4 + 2], acc);
            acc = fmaf(dv.w, wdt[g * 4 + 3], acc);
        }
        float dtv = softplusf_(acc);
        s += dtv;
        float uv = u[(row0 + t) * DIN + d];
        float du = dtv * uv;
        #pragma unroll
        for (int g = 0; g < 4; ++g) {
            float4 Bv = *(const float4*)&ds[t][32 + g * 4];
            h[g * 4 + 0] = fmaf(__expf(dtv * An[g * 4 + 0]), h[g * 4 + 0], du * Bv.x);
            h[g * 4 + 1] = fmaf(__expf(dtv * An[g * 4 + 1]), h[g * 4 + 1], du * Bv.y);
            h[g * 4 + 2] = fmaf(__expf(dtv * An[g * 4 + 2]), h[g * 4 + 2], du * Bv.z);
            h[g * 4 + 3] = fmaf(__expf(dtv * An[g * 4 + 3]), h[g * 4 + 3], du * Bv.w);
        }
    }
    float4* pp = (float4*)(part + ((size_t)(b * NCH + ch) * DIN + d) * DSTATE);
    pp[0] = make_float4(h[0], h[1], h[2], h[3]);
    pp[1] = make_float4(h[4], h[5], h[6], h[7]);
    pp[2] = make_float4(h[8], h[9], h[10], h[11]);
    pp[3] = make_float4(h[12], h[13], h[14], h[15]);
    sdt[(b * NCH + ch) * DIN + d] = s;
}

// ------------------------------------------------- chunked scan: phase B ----
// grid (B_*DIN*DSTATE/256). Combine chunk partials; store h_in for last 3 chunks.
__global__ void scanB(const float* __restrict__ part, const float* __restrict__ sdt,
                      const float* __restrict__ A_log, float* __restrict__ hin) {
    int gid = blockIdx.x * 256 + threadIdx.x;   // b*16384 + d*16 + n
    int b = gid >> 14;
    int rem = gid & 16383;
    int d = rem >> 4, n = rem & 15;
    float An = -__expf(A_log[d * DSTATE + n]);
    float h = 0.f;
    for (int c = 0; c < NCH; ++c) {
        if (c >= NCH - 3)
            hin[(((size_t)b * 3 + (c - (NCH - 3))) * DIN + d) * DSTATE + n] = h;
        float dec = __expf(An * sdt[(b * NCH + c) * DIN + d]);
        h = fmaf(dec, h, part[((size_t)(b * NCH + c) * DIN + d) * DSTATE + n]);
    }
}

// ------------------------------------------------- chunked scan: phase C ----
// grid (DIN/256, 3, B_): chunks 13..15 (t=416..511). Seed h from hin, step,
// emit yfin = (y + u*D) * zs.
__global__ __launch_bounds__(256) void scanC(const float* __restrict__ u,
        const float* __restrict__ dbc, const float* __restrict__ W_dt,
        const float* __restrict__ b_dt, const float* __restrict__ A_log,
        const float* __restrict__ Dv, const float* __restrict__ hin,
        const float* __restrict__ zs, float* __restrict__ yfin) {
    int b = blockIdx.z, c3 = blockIdx.y;
    int ch = (NCH - 3) + c3;
    int d = blockIdx.x * 256 + threadIdx.x;
    int tid = threadIdx.x;
    __shared__ float ds[CLEN][64];
    int row0 = b * L_ + ch * CLEN;
    {
        const float4* src = (const float4*)(dbc + row0 * 64);
        float4* dst = (float4*)&ds[0][0];
        dst[tid] = src[tid];
        dst[tid + 256] = src[tid + 256];
    }
    float wdt[DTRANK];
    #pragma unroll
    for (int k = 0; k < DTRANK; ++k) wdt[k] = W_dt[k * DIN + d];
    float bd = b_dt[d];
    float An[DSTATE], h[DSTATE];
    #pragma unroll
    for (int n = 0; n < DSTATE; ++n) An[n] = -__expf(A_log[d * DSTATE + n]);
    {
        const float4* hp = (const float4*)(hin + (((size_t)b * 3 + c3) * DIN + d) * DSTATE);
        float4 h0 = hp[0], h1 = hp[1], h2 = hp[2], h3 = hp[3];
        h[0] = h0.x; h[1] = h0.y; h[2] = h0.z; h[3] = h0.w;
        h[4] = h1.x; h[5] = h1.y; h[6] = h1.z; h[7] = h1.w;
        h[8] = h2.x; h[9] = h2.y; h[10] = h2.z; h[11] = h2.w;
        h[12] = h3.x; h[13] = h3.y; h[14] = h3.z; h[15] = h3.w;
    }
    float Dd = Dv[d];
    __syncthreads();
    for (int t = 0; t < CLEN; ++t) {
        float acc = bd;
        #pragma unroll
        for (int g = 0; g < 8; ++g) {
            float4 dv = *(const float4*)&ds[t][g * 4];
            acc = fmaf(dv.x, wdt[g * 4 + 0], acc);
            acc = fmaf(dv.y, wdt[g * 4 + 1], acc);
            acc = fmaf(dv.z, wdt[g * 4 + 2], acc);
            acc = fmaf(dv.w, wdt[g * 4 + 3], acc);
        }
        float dtv = softplusf_(acc);
        float uv = u[(row0 + t) * DIN + d];
        float du = dtv * uv;
        float y = 0.f;
        #pragma unroll
        for (int g = 0; g < 4; ++g) {
            float4 Bv = *(const float4*)&ds[t][32 + g * 4];
            float4 Cv = *(const float4*)&ds[t][48 + g * 4];
            h[g * 4 + 0] = fmaf(__expf(dtv * An[g * 4 + 0]), h[g * 4 + 0], du * Bv.x);
            h[g * 4 + 1] = fmaf(__expf(dtv * An[g * 4 + 1]), h[g * 4 + 1], du * Bv.y);
            h[g * 4 + 2] = fmaf(__expf(dtv * An[g * 4 + 2]), h[g * 4 + 2], du * Bv.z);
            h[g * 4 + 3] = fmaf(__expf(dtv * An[g * 4 + 3]), h[g * 4 + 3], du * Bv.w);
            y = fmaf(h[g * 4 + 0], Cv.x, y);
            y = fmaf(h[g * 4 + 1], Cv.y, y);
            y = fmaf(h[g * 4 + 2], Cv.z, y);
            y = fmaf(h[g * 4 + 3], Cv.w, y);
        }
        int tg = ch * CLEN + t;                        // 416..511
        size_t idx = ((size_t)(b * PRED) + (tg - L0T)) * DIN + d;
        yfin[idx] = (y + uv * Dd) * zs[idx];
    }
}

// ------------------------------------------------------- final project ----
__global__ void final_kernel(const float* __restrict__ yfin, const float* __restrict__ W_oh,
                             const float* __restrict__ mean, const float* __restrict__ stdv,
                             float* __restrict__ out) {
    int t96 = blockIdx.x, b = blockIdx.y;
    int lane = threadIdx.x;
    float p[COUT] = {};
    int base = ((b * PRED) + t96) * DIN;
    for (int j = lane; j < DIN; j += 64) {
        float yv = yfin[base + j];
        #pragma unroll
        for (int c = 0; c < COUT; ++c) p[c] = fmaf(yv, W_oh[j * COUT + c], p[c]);
    }
    #pragma unroll
    for (int off = 32; off; off >>= 1)
        #pragma unroll
        for (int c = 0; c < COUT; ++c) p[c] += __shfl_down(p[c], off);
    if (lane == 0) {
        #pragma unroll
        for (int c = 0; c < COUT; ++c)
            out[((b * PRED) + t96) * COUT + c] = p[c] * stdv[b * COUT + c] + mean[b * COUT + c];
    }
}

extern "C" void kernel_launch(void* const* d_in, const int* in_sizes, int n_in,
                              void* d_out, int out_size, void* d_ws, size_t ws_size,
                              hipStream_t stream) {
    const float* x_enc  = (const float*)d_in[0];
    const float* W_emb  = (const float*)d_in[1];
    const float* W_in   = (const float*)d_in[2];
    const float* conv_w = (const float*)d_in[3];
    const float* conv_b = (const float*)d_in[4];
    const float* W_xp   = (const float*)d_in[5];
    const float* W_dt   = (const float*)d_in[6];
    const float* b_dt   = (const float*)d_in[7];
    const float* A_log  = (const float*)d_in[8];
    const float* Dv     = (const float*)d_in[9];
    const float* W_out  = (const float*)d_in[10];
    const float* W_head = (const float*)d_in[11];
    float* out = (float*)d_out;

    float* W = (float*)d_ws;
    float* xn   = W;              W += B_ * L_ * ENC;        // 57344
    float* mean = W;              W += B_ * ENC;
    float* stdv = W;              W += B_ * ENC;
    float* W_ek = W;              W += 3 * ENC * XZC;        // 43008
    float* W_oh = W;              W += DIN * COUT;           // 7168
    float* pe   = W;              W += L_ * DM;              // 262144
    float* peW  = W;              W += L_ * XZC;             // 1048576
    float* u    = W;              W += B_ * L_ * DIN;        // 8388608
    float* zs   = W;              W += B_ * PRED * DIN;      // 1572864
    float* dbc  = W;              W += B_ * L_ * 64;         // 524288
    float* part = W;              W += B_ * NCH * DIN * DSTATE; // 4194304
    float* sdt  = W;              W += B_ * NCH * DIN;       // 262144
    float* hin  = W;              W += B_ * 3 * DIN * DSTATE;   // 786432
    float* yfin = W;              W += B_ * PRED * DIN;      // 1572864

    norm_kernel<<<B_ * ENC, 256, 0, stream>>>(x_enc, xn, mean, stdv);
    fold_wek<<<(3 * ENC * XZC) / 256, 256, 0, stream>>>(W_emb, W_in, W_ek);
    fold_woh<<<(DIN * COUT) / 256, 256, 0, stream>>>(W_out, W_head, W_oh);
    pe_kernel<<<(L_ * DM) / 256, 256, 0, stream>>>(pe);
    gemm_peW<<<160, 256, 0, stream>>>(pe, W_in, peW);
    u_kernel<<<dim3(DIN / 64, L_ / 64, B_), 256, 0, stream>>>(xn, W_ek, peW, conv_w, conv_b, u);
    z_kernel<<<dim3(4, 6, B_), 256, 0, stream>>>(xn, W_ek, peW, zs);
    dbc_kernel<<<(B_ * L_) / 16, 256, 0, stream>>>(u, W_xp, dbc);
    scanA<<<dim3(DIN / 256, NCH, B_), 256, 0, stream>>>(u, dbc, W_dt, b_dt, A_log, part, sdt);
    scanB<<<(B_ * DIN * DSTATE) / 256, 256, 0, stream>>>(part, sdt, A_log, hin);
    scanC<<<dim3(DIN / 256, 3, B_), 256, 0, stream>>>(u, dbc, W_dt, b_dt, A_log, Dv, hin, zs, yfin);
    final_kernel<<<dim3(PRED, B_), 64, 0, stream>>>(yfin, W_oh, mean, stdv, out);
}

// Round 3
// 284.735 us; speedup vs baseline: 1.9554x; 1.2640x over previous
//
#include <hip/hip_runtime.h>
#include <math.h>

// Problem constants
#define B_   16
#define L_   512
#define ENC  7
#define DM   512
#define DIN  1024
#define XZC  2048   // 2*DIN
#define DSTATE 16
#define DCONV  4
#define DTRANK 32
#define COUT 7
#define PRED 96
#define L0T  (L_ - PRED)   // 416
#define NCH  16
#define CLEN 32            // L_/NCH

__device__ __forceinline__ float sigmoidf_(float x) { return 1.f / (1.f + __expf(-x)); }
__device__ __forceinline__ float siluf_(float x) { return x * sigmoidf_(x); }
__device__ __forceinline__ float softplusf_(float x) {
    return (x > 20.f) ? x : __logf(1.f + __expf(x));
}

// ---------------------------------------------------------------- prep ----
// Fused independent preprocessing:
//  blocks [0,112): norm   [112,280): fold_wek   [280,308): fold_woh
//  [308,1332): pe         [1332,1396): AnT = -exp(A_log) transposed [n][d]
__global__ __launch_bounds__(256) void prep_kernel(
        const float* __restrict__ x, const float* __restrict__ W_emb,
        const float* __restrict__ W_in, const float* __restrict__ W_out,
        const float* __restrict__ W_head, const float* __restrict__ A_log,
        float* __restrict__ xn, float* __restrict__ mean, float* __restrict__ stdv,
        float* __restrict__ W_ek, float* __restrict__ W_oh, float* __restrict__ pe,
        float* __restrict__ AnT) {
    int blk = blockIdx.x;
    int tid = threadIdx.x;
    if (blk < 112) {
        int bc = blk;
        int b = bc / ENC, c = bc % ENC;
        float s = 0.f, s2 = 0.f;
        for (int l = tid; l < L_; l += 256) {
            float v = x[(b * L_ + l) * ENC + c];
            s += v; s2 += v * v;
        }
        #pragma unroll
        for (int off = 32; off; off >>= 1) {
            s  += __shfl_down(s, off);
            s2 += __shfl_down(s2, off);
        }
        __shared__ float rs[4], rs2[4], sm, ssd;
        int wave = tid >> 6, lane = tid & 63;
        if (lane == 0) { rs[wave] = s; rs2[wave] = s2; }
        __syncthreads();
        if (tid == 0) {
            float S = rs[0] + rs[1] + rs[2] + rs[3];
            float S2 = rs2[0] + rs2[1] + rs2[2] + rs2[3];
            float m = S / (float)L_;
            float var = S2 / (float)L_ - m * m;
            float sd = sqrtf(var + 1e-5f);
            mean[bc] = m; stdv[bc] = sd;
            sm = m; ssd = sd;
        }
        __syncthreads();
        float m = sm, sd = ssd;
        for (int l = tid; l < L_; l += 256) {
            int idx = (b * L_ + l) * ENC + c;
            xn[idx] = (x[idx] - m) / sd;
        }
    } else if (blk < 280) {
        int o = (blk - 112) * 256 + tid;             // < 43008
        int j = o & (XZC - 1);
        int kc = o >> 11;
        const float* we = W_emb + kc * DM;
        float s = 0.f;
        for (int d = 0; d < DM; ++d) s = fmaf(we[d], W_in[d * XZC + j], s);
        W_ek[o] = s;
    } else if (blk < 308) {
        int o = (blk - 280) * 256 + tid;             // < 7168
        int c = o % COUT, j = o / COUT;
        float s = 0.f;
        for (int d = 0; d < DM; ++d) s = fmaf(W_out[j * DM + d], W_head[d * COUT + c], s);
        W_oh[o] = s;
    } else if (blk < 1332) {
        int o = (blk - 308) * 256 + tid;             // < 262144
        int dcol = o & (DM - 1), l = o >> 9;
        int i2 = dcol >> 1;
        float div = __expf(-(float)(2 * i2) * (9.210340371976184f / (float)DM));
        float arg = (float)l * div;
        pe[o] = (dcol & 1) ? cosf(arg) : sinf(arg);
    } else {
        int o = (blk - 1332) * 256 + tid;            // < 16384: n*DIN+d
        int n = o >> 10, d = o & (DIN - 1);
        AnT[o] = -__expf(A_log[d * DSTATE + n]);
    }
}

// ------------------------------------------------- peW = pe @ W_in GEMM ----
// cols [0,1024) all rows; cols [1024,2048) rows 384..511. 160 blocks.
__global__ __launch_bounds__(256) void gemm_peW(const float* __restrict__ A,
                                                const float* __restrict__ Bm,
                                                float* __restrict__ C) {
    int bid = blockIdx.x;
    int m0, n0;
    if (bid < 128) { m0 = (bid >> 4) * 64; n0 = (bid & 15) * 64; }
    else { int q = bid - 128; m0 = 384 + (q >> 4) * 64; n0 = 1024 + (q & 15) * 64; }
    int tid = threadIdx.x;
    int tx = tid & 15, ty = tid >> 4;
    __shared__ float As[16][64];
    __shared__ float Bs[16][64];
    float acc[4][4] = {};
    for (int k0 = 0; k0 < DM; k0 += 16) {
        __syncthreads();
        #pragma unroll
        for (int q = 0; q < 4; ++q) {
            int f = tid + q * 256;
            int r = f >> 4, kk = f & 15;
            As[kk][r] = A[(m0 + r) * DM + k0 + kk];
        }
        #pragma unroll
        for (int q = 0; q < 4; ++q) {
            int f = tid + q * 256;
            int kk = f >> 6, c = f & 63;
            Bs[kk][c] = Bm[(k0 + kk) * XZC + n0 + c];
        }
        __syncthreads();
        #pragma unroll
        for (int kk = 0; kk < 16; ++kk) {
            float a[4], bb[4];
            #pragma unroll
            for (int i = 0; i < 4; ++i) a[i] = As[kk][ty * 4 + i];
            #pragma unroll
            for (int j = 0; j < 4; ++j) bb[j] = Bs[kk][tx * 4 + j];
            #pragma unroll
            for (int i = 0; i < 4; ++i)
                #pragma unroll
                for (int j = 0; j < 4; ++j) acc[i][j] = fmaf(a[i], bb[j], acc[i][j]);
        }
    }
    #pragma unroll
    for (int i = 0; i < 4; ++i)
        #pragma unroll
        for (int j = 0; j < 4; ++j)
            C[(m0 + ty * 4 + i) * XZC + n0 + tx * 4 + j] = acc[i][j];
}

// --------------------------------------- fused xm + depthwise conv + silu ----
__global__ __launch_bounds__(256) void u_kernel(const float* __restrict__ xn,
        const float* __restrict__ W_ek, const float* __restrict__ peW,
        const float* __restrict__ conv_w, const float* __restrict__ conv_b,
        float* __restrict__ u) {
    int b = blockIdx.z, l0 = blockIdx.y * 64, j0 = blockIdx.x * 64;
    int tid = threadIdx.x;
    int jl = tid & 63, lq = tid >> 6;
    int jg = j0 + jl;
    __shared__ float xmT[67][64];
    float wek[3][7];
    #pragma unroll
    for (int k = 0; k < 3; ++k)
        #pragma unroll
        for (int c = 0; c < 7; ++c)
            wek[k][c] = W_ek[(k * 7 + c) * XZC + jg];
    for (int r = lq; r < 67; r += 4) {
        int l = l0 - 3 + r;
        float v = 0.f;
        if (l >= 0) {
            v = peW[l * XZC + jg];
            #pragma unroll
            for (int k = 0; k < 3; ++k) {
                int lw = l + k - 1;
                lw = (lw < 0) ? (L_ - 1) : ((lw >= L_) ? lw - L_ : lw);
                const float* xr = xn + (b * L_ + lw) * ENC;
                #pragma unroll
                for (int c = 0; c < 7; ++c) v = fmaf(xr[c], wek[k][c], v);
            }
        }
        xmT[r][jl] = v;
    }
    __syncthreads();
    float cw0 = conv_w[0 * DIN + jg], cw1 = conv_w[1 * DIN + jg];
    float cw2 = conv_w[2 * DIN + jg], cw3 = conv_w[3 * DIN + jg];
    float cb = conv_b[jg];
    for (int r = lq; r < 64; r += 4) {
        int l = l0 + r;
        float s = cb;
        s = fmaf(xmT[r + 0][jl], cw0, s);
        s = fmaf(xmT[r + 1][jl], cw1, s);
        s = fmaf(xmT[r + 2][jl], cw2, s);
        s = fmaf(xmT[r + 3][jl], cw3, s);
        u[((b * L_) + l) * DIN + jg] = siluf_(s);
    }
}

// --------------------------------------- dbc (split-K GEMM, 2 partials) ----
// grid 256: (kh in {0,1}) x (128 row-tiles of 64). 64x64 tile, 4x4/thread.
// dbc_p[kh][row][64]; consumers add the two halves.
__global__ __launch_bounds__(256) void dbc_kernel(const float* __restrict__ u,
        const float* __restrict__ Wx, float* __restrict__ dbcp) {
    int kh = blockIdx.x >> 7;
    int m0 = (blockIdx.x & 127) * 64;
    int tid = threadIdx.x;
    int tx = tid & 15, ty = tid >> 4;
    __shared__ float As[32][64];   // [k][m]
    __shared__ float Bs[32][64];   // [k][n]
    float acc[4][4] = {};
    int kbase = kh * 512;
    int r = tid >> 2, g = tid & 3;
    int bk = tid >> 3, bc = (tid & 7) * 4;
    for (int k0 = 0; k0 < 512; k0 += 32) {
        __syncthreads();
        float4 a0 = *(const float4*)&u[(m0 + r) * DIN + kbase + k0 + g * 4];
        float4 a1 = *(const float4*)&u[(m0 + r) * DIN + kbase + k0 + 16 + g * 4];
        As[g * 4 + 0][r] = a0.x; As[g * 4 + 1][r] = a0.y;
        As[g * 4 + 2][r] = a0.z; As[g * 4 + 3][r] = a0.w;
        As[16 + g * 4 + 0][r] = a1.x; As[16 + g * 4 + 1][r] = a1.y;
        As[16 + g * 4 + 2][r] = a1.z; As[16 + g * 4 + 3][r] = a1.w;
        *(float4*)&Bs[bk][bc]      = *(const float4*)&Wx[(kbase + k0 + bk) * 64 + bc];
        *(float4*)&Bs[bk][bc + 32] = *(const float4*)&Wx[(kbase + k0 + bk) * 64 + bc + 32];
        __syncthreads();
        #pragma unroll
        for (int kk = 0; kk < 32; ++kk) {
            float4 av = *(const float4*)&As[kk][ty * 4];
            float4 bv = *(const float4*)&Bs[kk][tx * 4];
            float a[4] = {av.x, av.y, av.z, av.w};
            float bb[4] = {bv.x, bv.y, bv.z, bv.w};
            #pragma unroll
            for (int i = 0; i < 4; ++i)
                #pragma unroll
                for (int j = 0; j < 4; ++j) acc[i][j] = fmaf(a[i], bb[j], acc[i][j]);
        }
    }
    #pragma unroll
    for (int i = 0; i < 4; ++i)
        *(float4*)&dbcp[((kh * 8192) + (m0 + ty * 4 + i)) * 64 + tx * 4] =
            make_float4(acc[i][0], acc[i][1], acc[i][2], acc[i][3]);
}

// ------------------------------------------------- chunked scan: phase A ----
// grid (4, NCH, B_). LDS-staged dbc (summed halves) + u tile; dt precomputed
// with 4-way ILP; local scan h=0; outputs partial h (16) + sum_dt per (b,ch,d).
__global__ __launch_bounds__(256) void scanA(const float* __restrict__ u,
        const float* __restrict__ dbcp, const float* __restrict__ W_dt,
        const float* __restrict__ b_dt, const float* __restrict__ AnT,
        float* __restrict__ part, float* __restrict__ sdt) {
    int b = blockIdx.z, ch = blockIdx.y;
    int d0 = blockIdx.x * 256;
    int tid = threadIdx.x;
    int d = d0 + tid;
    __shared__ float ds[CLEN][64];
    __shared__ float us[CLEN][256];
    int row0 = b * L_ + ch * CLEN;
    {
        const float4* s0 = (const float4*)(dbcp + row0 * 64);
        const float4* s1 = (const float4*)(dbcp + (8192 + row0) * 64);
        float4* dst = (float4*)&ds[0][0];
        float4 a = s0[tid], bb = s1[tid];
        dst[tid] = make_float4(a.x + bb.x, a.y + bb.y, a.z + bb.z, a.w + bb.w);
        a = s0[tid + 256]; bb = s1[tid + 256];
        dst[tid + 256] = make_float4(a.x + bb.x, a.y + bb.y, a.z + bb.z, a.w + bb.w);
        #pragma unroll
        for (int q = 0; q < 8; ++q) {
            int f = tid + q * 256;
            int rr = f >> 6, cg = (f & 63) * 4;
            *(float4*)&us[rr][cg] = *(const float4*)&u[(row0 + rr) * DIN + d0 + cg];
        }
    }
    float wdt[DTRANK];
    #pragma unroll
    for (int k = 0; k < DTRANK; ++k) wdt[k] = W_dt[k * DIN + d];
    float bd = b_dt[d];
    float An[DSTATE];
    #pragma unroll
    for (int n = 0; n < DSTATE; ++n) An[n] = AnT[n * DIN + d];
    __syncthreads();
    float dtv[CLEN];
    for (int t0 = 0; t0 < CLEN; t0 += 4) {
        float a0 = bd, a1 = bd, a2 = bd, a3 = bd;
        #pragma unroll
        for (int k = 0; k < DTRANK; k += 4) {
            float4 q0 = *(const float4*)&ds[t0 + 0][k];
            float4 q1 = *(const float4*)&ds[t0 + 1][k];
            float4 q2 = *(const float4*)&ds[t0 + 2][k];
            float4 q3 = *(const float4*)&ds[t0 + 3][k];
            a0 = fmaf(q0.x, wdt[k], a0); a0 = fmaf(q0.y, wdt[k+1], a0);
            a0 = fmaf(q0.z, wdt[k+2], a0); a0 = fmaf(q0.w, wdt[k+3], a0);
            a1 = fmaf(q1.x, wdt[k], a1); a1 = fmaf(q1.y, wdt[k+1], a1);
            a1 = fmaf(q1.z, wdt[k+2], a1); a1 = fmaf(q1.w, wdt[k+3], a1);
            a2 = fmaf(q2.x, wdt[k], a2); a2 = fmaf(q2.y, wdt[k+1], a2);
            a2 = fmaf(q2.z, wdt[k+2], a2); a2 = fmaf(q2.w, wdt[k+3], a2);
            a3 = fmaf(q3.x, wdt[k], a3); a3 = fmaf(q3.y, wdt[k+1], a3);
            a3 = fmaf(q3.z, wdt[k+2], a3); a3 = fmaf(q3.w, wdt[k+3], a3);
        }
        dtv[t0 + 0] = softplusf_(a0);
        dtv[t0 + 1] = softplusf_(a1);
        dtv[t0 + 2] = softplusf_(a2);
        dtv[t0 + 3] = softplusf_(a3);
    }
    float h[DSTATE];
    #pragma unroll
    for (int n = 0; n < DSTATE; ++n) h[n] = 0.f;
    float s = 0.f;
    for (int t = 0; t < CLEN; ++t) {
        float dt_t = dtv[t];
        s += dt_t;
        float du = dt_t * us[t][tid];
        #pragma unroll
        for (int g = 0; g < 4; ++g) {
            float4 Bv = *(const float4*)&ds[t][32 + g * 4];
            h[g*4+0] = fmaf(__expf(dt_t * An[g*4+0]), h[g*4+0], du * Bv.x);
            h[g*4+1] = fmaf(__expf(dt_t * An[g*4+1]), h[g*4+1], du * Bv.y);
            h[g*4+2] = fmaf(__expf(dt_t * An[g*4+2]), h[g*4+2], du * Bv.z);
            h[g*4+3] = fmaf(__expf(dt_t * An[g*4+3]), h[g*4+3], du * Bv.w);
        }
    }
    if (ch < NCH - 1) {
        float4* pp = (float4*)(part + ((size_t)(b * NCH + ch) * DIN + d) * DSTATE);
        pp[0] = make_float4(h[0], h[1], h[2], h[3]);
        pp[1] = make_float4(h[4], h[5], h[6], h[7]);
        pp[2] = make_float4(h[8], h[9], h[10], h[11]);
        pp[3] = make_float4(h[12], h[13], h[14], h[15]);
        sdt[(b * NCH + ch) * DIN + d] = s;
    }
}

// ------------------------------------------------- chunked scan: phase B ----
__global__ void scanB(const float* __restrict__ part, const float* __restrict__ sdt,
                      const float* __restrict__ A_log, float* __restrict__ hin) {
    int gid = blockIdx.x * 256 + threadIdx.x;   // b*16384 + d*16 + n
    int b = gid >> 14;
    int rem = gid & 16383;
    int d = rem >> 4, n = rem & 15;
    float An = -__expf(A_log[d * DSTATE + n]);
    float h = 0.f;
    for (int c = 0; c < NCH - 1; ++c) {
        float dec = __expf(An * sdt[(b * NCH + c) * DIN + d]);
        float hn = fmaf(dec, h, part[((size_t)(b * NCH + c) * DIN + d) * DSTATE + n]);
        if (c >= NCH - 4)
            hin[(((size_t)b * 3 + (c - (NCH - 4))) * DIN + d) * DSTATE + n] = hn;
        h = hn;
    }
}

// ------------------------------------------------- chunked scan: phase C ----
// chunks 13..15 (t=416..511). Seeds from hin; z (silu gate) computed inline;
// emits yfin = (y + u*D) * silu(z).
__global__ __launch_bounds__(256) void scanC(const float* __restrict__ u,
        const float* __restrict__ dbcp, const float* __restrict__ W_dt,
        const float* __restrict__ b_dt, const float* __restrict__ AnT,
        const float* __restrict__ Dv, const float* __restrict__ hin,
        const float* __restrict__ xn, const float* __restrict__ W_ek,
        const float* __restrict__ peW, float* __restrict__ yfin) {
    int b = blockIdx.z, c3 = blockIdx.y;
    int ch = (NCH - 3) + c3;
    int d0 = blockIdx.x * 256;
    int tid = threadIdx.x;
    int d = d0 + tid;
    __shared__ float ds[CLEN][64];
    __shared__ float us[CLEN][256];
    __shared__ float pw[CLEN][256];
    int row0 = b * L_ + ch * CLEN;
    int l0 = ch * CLEN;
    {
        const float4* s0 = (const float4*)(dbcp + row0 * 64);
        const float4* s1 = (const float4*)(dbcp + (8192 + row0) * 64);
        float4* dst = (float4*)&ds[0][0];
        float4 a = s0[tid], bb = s1[tid];
        dst[tid] = make_float4(a.x + bb.x, a.y + bb.y, a.z + bb.z, a.w + bb.w);
        a = s0[tid + 256]; bb = s1[tid + 256];
        dst[tid + 256] = make_float4(a.x + bb.x, a.y + bb.y, a.z + bb.z, a.w + bb.w);
        #pragma unroll
        for (int q = 0; q < 8; ++q) {
            int f = tid + q * 256;
            int rr = f >> 6, cg = (f & 63) * 4;
            *(float4*)&us[rr][cg] = *(const float4*)&u[(row0 + rr) * DIN + d0 + cg];
            *(float4*)&pw[rr][cg] = *(const float4*)&peW[(l0 + rr) * XZC + DIN + d0 + cg];
        }
    }
    float wdt[DTRANK];
    #pragma unroll
    for (int k = 0; k < DTRANK; ++k) wdt[k] = W_dt[k * DIN + d];
    float bd = b_dt[d];
    float An[DSTATE], h[DSTATE];
    #pragma unroll
    for (int n = 0; n < DSTATE; ++n) An[n] = AnT[n * DIN + d];
    {
        const float4* hp = (const float4*)(hin + (((size_t)b * 3 + c3) * DIN + d) * DSTATE);
        float4 h0 = hp[0], h1 = hp[1], h2 = hp[2], h3 = hp[3];
        h[0] = h0.x; h[1] = h0.y; h[2] = h0.z; h[3] = h0.w;
        h[4] = h1.x; h[5] = h1.y; h[6] = h1.z; h[7] = h1.w;
        h[8] = h2.x; h[9] = h2.y; h[10] = h2.z; h[11] = h2.w;
        h[12] = h3.x; h[13] = h3.y; h[14] = h3.z; h[15] = h3.w;
    }
    float wekz[21];
    #pragma unroll
    for (int kc = 0; kc < 21; ++kc) wekz[kc] = W_ek[kc * XZC + DIN + d];
    float Dd = Dv[d];
    __syncthreads();
    for (int t = 0; t < CLEN; ++t) {
        float acc = bd;
        #pragma unroll
        for (int g = 0; g < 8; ++g) {
            float4 dv = *(const float4*)&ds[t][g * 4];
            acc = fmaf(dv.x, wdt[g * 4 + 0], acc);
            acc = fmaf(dv.y, wdt[g * 4 + 1], acc);
            acc = fmaf(dv.z, wdt[g * 4 + 2], acc);
            acc = fmaf(dv.w, wdt[g * 4 + 3], acc);
        }
        float dtv = softplusf_(acc);
        float uv = us[t][tid];
        float du = dtv * uv;
        float y = 0.f;
        #pragma unroll
        for (int g = 0; g < 4; ++g) {
            float4 Bv = *(const float4*)&ds[t][32 + g * 4];
            float4 Cv = *(const float4*)&ds[t][48 + g * 4];
            h[g*4+0] = fmaf(__expf(dtv * An[g*4+0]), h[g*4+0], du * Bv.x);
            h[g*4+1] = fmaf(__expf(dtv * An[g*4+1]), h[g*4+1], du * Bv.y);
            h[g*4+2] = fmaf(__expf(dtv * An[g*4+2]), h[g*4+2], du * Bv.z);
            h[g*4+3] = fmaf(__expf(dtv * An[g*4+3]), h[g*4+3], du * Bv.w);
            y = fmaf(h[g*4+0], Cv.x, y);
            y = fmaf(h[g*4+1], Cv.y, y);
            y = fmaf(h[g*4+2], Cv.z, y);
            y = fmaf(h[g*4+3], Cv.w, y);
        }
        // inline z gate
        int l = l0 + t;   // 416..511
        float zv = pw[t][tid];
        #pragma unroll
        for (int k = 0; k < 3; ++k) {
            int lw = l + k - 1;
            if (lw >= L_) lw -= L_;
            const float* xr = xn + (b * L_ + lw) * ENC;
            #pragma unroll
            for (int c = 0; c < 7; ++c) zv = fmaf(xr[c], wekz[k * 7 + c], zv);
        }
        int idx = ((b * PRED) + (l - L0T)) * DIN + d;
        yfin[idx] = (y + uv * Dd) * siluf_(zv);
    }
}

// ------------------------------------------------------- final project ----
__global__ void final_kernel(const float* __restrict__ yfin, const float* __restrict__ W_oh,
                             const float* __restrict__ mean, const float* __restrict__ stdv,
                             float* __restrict__ out) {
    int t96 = blockIdx.x, b = blockIdx.y;
    int lane = threadIdx.x;
    float p[COUT] = {};
    int base = ((b * PRED) + t96) * DIN;
    for (int j = lane; j < DIN; j += 64) {
        float yv = yfin[base + j];
        #pragma unroll
        for (int c = 0; c < COUT; ++c) p[c] = fmaf(yv, W_oh[j * COUT + c], p[c]);
    }
    #pragma unroll
    for (int off = 32; off; off >>= 1)
        #pragma unroll
        for (int c = 0; c < COUT; ++c) p[c] += __shfl_down(p[c], off);
    if (lane == 0) {
        #pragma unroll
        for (int c = 0; c < COUT; ++c)
            out[((b * PRED) + t96) * COUT + c] = p[c] * stdv[b * COUT + c] + mean[b * COUT + c];
    }
}

extern "C" void kernel_launch(void* const* d_in, const int* in_sizes, int n_in,
                              void* d_out, int out_size, void* d_ws, size_t ws_size,
                              hipStream_t stream) {
    const float* x_enc  = (const float*)d_in[0];
    const float* W_emb  = (const float*)d_in[1];
    const float* W_in   = (const float*)d_in[2];
    const float* conv_w = (const float*)d_in[3];
    const float* conv_b = (const float*)d_in[4];
    const float* W_xp   = (const float*)d_in[5];
    const float* W_dt   = (const float*)d_in[6];
    const float* b_dt   = (const float*)d_in[7];
    const float* A_log  = (const float*)d_in[8];
    const float* Dv     = (const float*)d_in[9];
    const float* W_out  = (const float*)d_in[10];
    const float* W_head = (const float*)d_in[11];
    float* out = (float*)d_out;

    float* W = (float*)d_ws;
    float* xn   = W;              W += B_ * L_ * ENC;           // 57344
    float* mean = W;              W += B_ * ENC;
    float* stdv = W;              W += B_ * ENC;
    float* W_ek = W;              W += 3 * ENC * XZC;           // 43008
    float* W_oh = W;              W += DIN * COUT;              // 7168
    float* pe   = W;              W += L_ * DM;                 // 262144
    float* peW  = W;              W += L_ * XZC;                // 1048576
    float* AnT  = W;              W += DSTATE * DIN;            // 16384
    float* u    = W;              W += B_ * L_ * DIN;           // 8388608
    float* dbcp = W;              W += 2 * B_ * L_ * 64;        // 1048576
    float* part = W;              W += B_ * NCH * DIN * DSTATE; // 4194304
    float* sdt  = W;              W += B_ * NCH * DIN;          // 262144
    float* hin  = W;              W += B_ * 3 * DIN * DSTATE;   // 786432
    float* yfin = W;              W += B_ * PRED * DIN;         // 1572864

    prep_kernel<<<1396, 256, 0, stream>>>(x_enc, W_emb, W_in, W_out, W_head, A_log,
                                          xn, mean, stdv, W_ek, W_oh, pe, AnT);
    gemm_peW<<<160, 256, 0, stream>>>(pe, W_in, peW);
    u_kernel<<<dim3(DIN / 64, L_ / 64, B_), 256, 0, stream>>>(xn, W_ek, peW, conv_w, conv_b, u);
    dbc_kernel<<<256, 256, 0, stream>>>(u, W_xp, dbcp);
    scanA<<<dim3(DIN / 256, NCH, B_), 256, 0, stream>>>(u, dbcp, W_dt, b_dt, AnT, part, sdt);
    scanB<<<(B_ * DIN * DSTATE) / 256, 256, 0, stream>>>(part, sdt, A_log, hin);
    scanC<<<dim3(DIN / 256, 3, B_), 256, 0, stream>>>(u, dbcp, W_dt, b_dt, AnT, Dv, hin,
                                                      xn, W_ek, peW, yfin);
    final_kernel<<<dim3(PRED, B_), 64, 0, stream>>>(yfin, W_oh, mean, stdv, out);
}